// Round 5
// baseline (907.258 us; speedup 1.0000x reference)
//
#include <hip/hip_runtime.h>
#include <math.h>
#include <stdint.h>

// ---------------- problem constants ----------------
#define CHH 100
#define CWW 152
#define NPIX 15200          // 100*152
#define NANCH 136800        // NPIX*9
#define NPRE 6000
#define NPOST 300
#define CANDCAP 8192
#define MROW 96             // u64 words per mask row (94 used, padded)

// padded pixel geometry for the MFMA conv: pp = (py+1)*154 + (px+1)
#define PSTRIDE 154
#define PPVALID 16016       // 154*104 region containing all shifted accesses
#define PPS 16128           // padded to 126 tiles of 128
#define XGUARD 256          // zero guard rows each side of the [0,PPS) range
#define XROWS_TOTAL (PPS + 2*XGUARD)   // 16640

// LDS tile inner dim: 40 f16 (80 B row stride = 5 16B-groups, coprime with 8 -> conflict-free)
#define LPAD 40

// ---------------- ws layout (bytes) ----------------
#define WTH_OFF  0ull                  // w taps hi: [9][512][512] f16 = 4,718,592
#define WTL_OFF  4718592ull            // w taps lo
#define WX_OFF   9437184ull            // 1x1 weights transposed: [512][54] f32
#define XH_OFF   9547776ull            // x hi plane: [16640][512] f16 = 17,039,360
#define XL_OFF   26587136ull           // x lo plane
#define H_OFF    43626496ull           // hidden: [512][16128] f32 = 33,030,144 (reused as NMS mask)
#define ROI_OFF  76656640ull           // roi: [136800][4] f32
#define SC_OFF   78845440ull           // sc: [136800] f32
#define CTL_OFF  79392640ull           // Ctl struct
#define CAND_OFF 79396736ull           // cand: [8192] u64
#define SBOX_OFF 79462272ull           // sorted boxes: [6000] float4

typedef _Float16 f16x8 __attribute__((ext_vector_type(8)));
typedef float    f32x4 __attribute__((ext_vector_type(4)));

struct Ctl {
  unsigned hist[256];
  unsigned prefix;
  unsigned countGreater;
  unsigned candCount;
  unsigned done;
};

struct AnchorArg { float v[36]; };

__device__ __forceinline__ unsigned mono_key(float f) {
  unsigned u = __float_as_uint(f);
  return u ^ ((u & 0x80000000u) ? 0xFFFFFFFFu : 0x80000000u);
}

// ---------------- K1: combined 1x1 weights + ctl init ----------------
__global__ void wx_kernel(const float* __restrict__ score_w, const float* __restrict__ loc_w,
                          float* __restrict__ wx, Ctl* __restrict__ ctl) {
  int i = blockIdx.x * 256 + threadIdx.x;
  if (blockIdx.x == 0) {
    int t = threadIdx.x;
    ctl->hist[t] = 0u;
    if (t == 0) { ctl->prefix = 0u; ctl->countGreater = 0u; ctl->candCount = 0u; ctl->done = 0u; }
  }
  if (i >= 512 * 54) return;
  int ic = i / 54, oc = i - ic * 54;
  wx[i] = (oc < 18) ? score_w[oc * 512 + ic] : loc_w[(oc - 18) * 512 + ic];
}

// ---------------- K2: split conv1 weights into per-tap f16 hi/lo planes ----------------
__global__ __launch_bounds__(256) void prep_w_kernel(const float* __restrict__ w1,
                                                     _Float16* __restrict__ wtapH,
                                                     _Float16* __restrict__ wtapL) {
  __shared__ float wl[4608];
  const int oc = blockIdx.x, tid = threadIdx.x;
  for (int li = tid; li < 4608; li += 256) wl[li] = w1[(size_t)oc * 4608 + li];
  __syncthreads();
  for (int t = 0; t < 9; ++t) {
    size_t ob = ((size_t)t * 512 + oc) * 512;
    for (int ic = tid; ic < 512; ic += 256) {
      float v = wl[ic * 9 + t];
      _Float16 hi = (_Float16)v;
      wtapH[ob + ic] = hi;
      wtapL[ob + ic] = (_Float16)(v - (float)hi);
    }
  }
}

// ---------------- K3: transpose+pad+split input: x [512][15200] -> xh/xl [16640][512] ----
__global__ __launch_bounds__(256) void prep_x_kernel(const float* __restrict__ x,
                                                     _Float16* __restrict__ xh,
                                                     _Float16* __restrict__ xl) {
  __shared__ float tile[64][65];
  const int tid = threadIdx.x;
  const int r0 = blockIdx.x * 64;                // alloc-row base (0..16640)
  for (int ic0 = 0; ic0 < 512; ic0 += 64) {
    #pragma unroll
    for (int it = 0; it < 16; ++it) {
      int li = it * 256 + tid;
      int i = li >> 6, j = li & 63;
      int pp = r0 + j - XGUARD;
      float v = 0.f;
      if (pp >= 0 && pp < PPVALID) {
        int rowp = pp / PSTRIDE, colp = pp - rowp * PSTRIDE;
        if (rowp >= 1 && rowp <= 100 && colp >= 1 && colp <= 152) {
          int p = (rowp - 1) * CWW + (colp - 1);
          v = x[(size_t)(ic0 + i) * NPIX + p];
        }
      }
      tile[i][j] = v;
    }
    __syncthreads();
    int j = tid >> 2, cq = tid & 3;
    size_t ob = (size_t)(r0 + j) * 512 + ic0 + cq * 16;
    #pragma unroll
    for (int c = 0; c < 16; ++c) {
      float v = tile[cq * 16 + c][j];
      _Float16 hi = (_Float16)v;
      xh[ob + c] = hi;
      xl[ob + c] = (_Float16)(v - (float)hi);
    }
    __syncthreads();
  }
}

// ---------------- K4: conv1 as split-f16 MFMA implicit GEMM ----------------
__global__ __launch_bounds__(256) void conv1_mfma_kernel(const _Float16* __restrict__ xh,
                                                         const _Float16* __restrict__ xl,
                                                         const _Float16* __restrict__ wtapH,
                                                         const _Float16* __restrict__ wtapL,
                                                         const float* __restrict__ bias,
                                                         float* __restrict__ h) {
  __shared__ _Float16 Ah[128][LPAD], Al[128][LPAD], Bh[128][LPAD], Bl[128][LPAD];
  __shared__ float bsm[128];
  const int tid = threadIdx.x;
  const int oc0 = blockIdx.x * 128;   // 4 oc tiles (fast-varying -> adjacent dispatch ids share B)
  const int pp0 = blockIdx.y * 128;   // 126 pp tiles
  if (tid < 128) bsm[tid] = bias[oc0 + tid];

  const int lane = tid & 63;
  const int n16 = lane & 15, quad = lane >> 4;
  const int wid = tid >> 6;
  const int wm = wid >> 1, wn = wid & 1;
  const int srow = tid >> 2, sq = tid & 3;

  f32x4 acc[4][4];
  #pragma unroll
  for (int mi = 0; mi < 4; ++mi)
    #pragma unroll
    for (int ni = 0; ni < 4; ++ni) acc[mi][ni] = (f32x4){0.f, 0.f, 0.f, 0.f};

  for (int t = 0; t < 9; ++t) {
    const int dsh = (t / 3 - 1) * PSTRIDE + (t % 3) - 1;
    const size_t wbase = ((size_t)t * 512 + oc0) * 512;
    for (int icb = 0; icb < 512; icb += 32) {
      #pragma unroll
      for (int hf = 0; hf < 2; ++hf) {
        int row = hf * 64 + srow;
        size_t wo = wbase + (size_t)row * 512 + icb + sq * 8;
        *(f16x8*)&Ah[row][sq * 8] = *(const f16x8*)&wtapH[wo];
        *(f16x8*)&Al[row][sq * 8] = *(const f16x8*)&wtapL[wo];
        size_t xo = (size_t)(pp0 + row + dsh) * 512 + icb + sq * 8;
        *(f16x8*)&Bh[row][sq * 8] = *(const f16x8*)&xh[xo];
        *(f16x8*)&Bl[row][sq * 8] = *(const f16x8*)&xl[xo];
      }
      __syncthreads();
      f16x8 ah[4], al[4], bh[4], bl[4];
      #pragma unroll
      for (int mi = 0; mi < 4; ++mi) {
        ah[mi] = *(const f16x8*)&Ah[wm * 64 + mi * 16 + n16][quad * 8];
        al[mi] = *(const f16x8*)&Al[wm * 64 + mi * 16 + n16][quad * 8];
      }
      #pragma unroll
      for (int ni = 0; ni < 4; ++ni) {
        bh[ni] = *(const f16x8*)&Bh[wn * 64 + ni * 16 + n16][quad * 8];
        bl[ni] = *(const f16x8*)&Bl[wn * 64 + ni * 16 + n16][quad * 8];
      }
      #pragma unroll
      for (int mi = 0; mi < 4; ++mi)
        #pragma unroll
        for (int ni = 0; ni < 4; ++ni) {
          acc[mi][ni] = __builtin_amdgcn_mfma_f32_16x16x32_f16(ah[mi], bh[ni], acc[mi][ni], 0, 0, 0);
          acc[mi][ni] = __builtin_amdgcn_mfma_f32_16x16x32_f16(ah[mi], bl[ni], acc[mi][ni], 0, 0, 0);
          acc[mi][ni] = __builtin_amdgcn_mfma_f32_16x16x32_f16(al[mi], bh[ni], acc[mi][ni], 0, 0, 0);
        }
      __syncthreads();
    }
  }
  #pragma unroll
  for (int mi = 0; mi < 4; ++mi) {
    int ocb = wm * 64 + mi * 16 + quad * 4;
    #pragma unroll
    for (int ni = 0; ni < 4; ++ni) {
      int pp = pp0 + wn * 64 + ni * 16 + n16;
      #pragma unroll
      for (int r = 0; r < 4; ++r) {
        float v = acc[mi][ni][r] + bsm[ocb + r];
        h[(size_t)(oc0 + ocb + r) * PPS + pp] = fmaxf(v, 0.f);
      }
    }
  }
}

// ---------------- K5: 1x1 heads + softmax + loc2bbox + clip + valid ----------------
__global__ __launch_bounds__(256) void heads_kernel(const float* __restrict__ h,
                                                    const float* __restrict__ wx,
                                                    const float* __restrict__ score_b,
                                                    const float* __restrict__ loc_b,
                                                    float* __restrict__ rpn_loc,
                                                    float* __restrict__ rpn_score,
                                                    float* __restrict__ roi,
                                                    float* __restrict__ sc,
                                                    AnchorArg ab,
                                                    const int* __restrict__ ihp,
                                                    const int* __restrict__ iwp) {
  __shared__ float hs[64][64];
  __shared__ float red[54][64];
  const int tid = threadIdx.x;
  const int p0 = blockIdx.x * 64;
  const int pxl = tid & 63, icq = tid >> 6;
  int pcol = p0 + pxl;
  bool pok = pcol < NPIX;
  int ppl = 0;
  if (pok) ppl = (pcol / CWW + 1) * PSTRIDE + (pcol % CWW) + 1;

  float acc[54];
  #pragma unroll
  for (int o = 0; o < 54; ++o) acc[o] = 0.f;

  for (int c = 0; c < 8; ++c) {
    int ic0 = c * 64;
    #pragma unroll
    for (int r = 0; r < 16; ++r) {
      int i = r * 4 + icq;
      hs[i][pxl] = pok ? h[(size_t)(ic0 + i) * PPS + ppl] : 0.f;
    }
    __syncthreads();
    #pragma unroll
    for (int k = 0; k < 16; ++k) {
      int icl = icq + k * 4;
      float v = hs[icl][pxl];
      const float* wrow = &wx[(ic0 + icl) * 54];
      #pragma unroll
      for (int o = 0; o < 54; ++o) acc[o] += wrow[o] * v;
    }
    __syncthreads();
  }
  for (int w = 0; w < 4; ++w) {
    if (icq == w) {
      if (w == 0) {
        #pragma unroll
        for (int o = 0; o < 54; ++o) red[o][pxl] = acc[o];
      } else {
        #pragma unroll
        for (int o = 0; o < 54; ++o) red[o][pxl] += acc[o];
      }
    }
    __syncthreads();
  }

  const float fH = (float)(*ihp);
  const float fW = (float)(*iwp);
  for (int it = tid; it < 576; it += 256) {
    #pragma clang fp contract(off)
    int pl = it / 9, a = it - pl * 9;
    int p = p0 + pl;
    if (p >= NPIX) continue;
    float s0 = red[a * 2][pl]     + score_b[a * 2];
    float s1 = red[a * 2 + 1][pl] + score_b[a * 2 + 1];
    float dy = red[18 + a * 4][pl]     + loc_b[a * 4];
    float dx = red[18 + a * 4 + 1][pl] + loc_b[a * 4 + 1];
    float dh = red[18 + a * 4 + 2][pl] + loc_b[a * 4 + 2];
    float dw = red[18 + a * 4 + 3][pl] + loc_b[a * 4 + 3];
    int row = p * 9 + a;
    *(float2*)&rpn_score[row * 2] = make_float2(s0, s1);
    *(float4*)&rpn_loc[(size_t)row * 4] = make_float4(dy, dx, dh, dw);
    int ypix = p / CWW, xpix = p - ypix * CWW;
    float sy = (float)(ypix * 16), sx = (float)(xpix * 16);
    float a0 = sy + ab.v[a * 4 + 0], a1 = sx + ab.v[a * 4 + 1];
    float a2 = sy + ab.v[a * 4 + 2], a3 = sx + ab.v[a * 4 + 3];
    float ha = a2 - a0, wa = a3 - a1;
    float cy = a0 + 0.5f * ha, cx = a1 + 0.5f * wa;
    float cy2 = dy * ha + cy, cx2 = dx * wa + cx;
    float h2 = expf(dh) * ha, w2 = expf(dw) * wa;
    float y1 = cy2 - 0.5f * h2, x1 = cx2 - 0.5f * w2;
    float y2 = cy2 + 0.5f * h2, x2 = cx2 + 0.5f * w2;
    y1 = fminf(fmaxf(y1, 0.f), fH); x1 = fminf(fmaxf(x1, 0.f), fW);
    y2 = fminf(fmaxf(y2, 0.f), fH); x2 = fminf(fmaxf(x2, 0.f), fW);
    *(float4*)&roi[(size_t)row * 4] = make_float4(y1, x1, y2, x2);
    bool valid = (y2 - y1 >= 16.f) && (x2 - x1 >= 16.f);
    float m  = fmaxf(s0, s1);
    float e0 = expf(s0 - m), e1 = expf(s1 - m);
    float fg = e1 / (e0 + e1);
    sc[row] = valid ? fg : -__builtin_inff();
  }
}

// ---------------- K6: fused radix histogram + last-block scan ----------------
#define HGRID 120
__global__ __launch_bounds__(256) void hist_scan_kernel(const float* __restrict__ sc,
                                                        Ctl* __restrict__ ctl, int pass) {
  __shared__ unsigned hloc[256];
  __shared__ unsigned ticket_s;
  int tid = threadIdx.x;
  hloc[tid] = 0u;
  __syncthreads();
  unsigned prefix = ctl->prefix;    // written by previous kernel (boundary-coherent)
  for (int i = blockIdx.x * 256 + tid; i < NANCH; i += HGRID * 256) {
    unsigned m = mono_key(sc[i]);
    bool pred = (pass == 0) || ((m >> (32 - 8 * pass)) == prefix);
    if (pred) atomicAdd(&hloc[(m >> (24 - 8 * pass)) & 255u], 1u);
  }
  __syncthreads();
  if (hloc[tid]) atomicAdd(&ctl->hist[tid], hloc[tid]);
  __threadfence();
  __syncthreads();
  if (tid == 0) ticket_s = atomicAdd(&ctl->done, 1u);
  __syncthreads();
  if (ticket_s != HGRID - 1) return;
  // last-to-finish block: suffix-scan the histogram, pick digit, reset state
  unsigned v = atomicExch(&ctl->hist[tid], 0u);   // device-coherent read + zero for next pass
  hloc[tid] = v;
  __syncthreads();
  for (int d = 1; d < 256; d <<= 1) {
    unsigned t2 = hloc[tid] + ((tid + d < 256) ? hloc[tid + d] : 0u);
    __syncthreads();
    hloc[tid] = t2;
    __syncthreads();
  }
  unsigned G = ctl->countGreater;
  unsigned inclT = hloc[tid];
  unsigned inclN = (tid < 255) ? hloc[tid + 1] : 0u;
  if (G + inclT >= (unsigned)NPRE && G + inclN < (unsigned)NPRE) {
    ctl->prefix = (prefix << 8) | (unsigned)tid;
    ctl->countGreater = G + inclN;
  }
  if (tid == 0) atomicExch(&ctl->done, 0u);
}

// ---------------- K8: compact candidates ----------------
__global__ __launch_bounds__(256) void compact_kernel(const float* __restrict__ sc,
                                                      Ctl* __restrict__ ctl,
                                                      unsigned long long* __restrict__ cand) {
  int i = blockIdx.x * 256 + threadIdx.x;
  unsigned prefix = ctl->prefix;
  bool pred = false; unsigned m = 0;
  if (i < NANCH) { m = mono_key(sc[i]); pred = ((m >> 8) >= prefix); }
  unsigned long long mask = __ballot(pred);
  if (mask) {
    int lane = threadIdx.x & 63;
    int leader = __ffsll((long long)mask) - 1;
    unsigned base = 0;
    if (lane == leader) base = atomicAdd(&ctl->candCount, (unsigned)__popcll(mask));
    base = __shfl(base, leader);
    if (pred) {
      unsigned slot = base + (unsigned)__popcll(mask & ((1ull << lane) - 1ull));
      if (slot < CANDCAP)
        cand[slot] = (((unsigned long long)(~m)) << 32) | (unsigned)i;
    }
  }
}

// ---------------- K9: single-block bitonic sort; gather boxes ----------------
__global__ __launch_bounds__(1024) void sort_kernel(const unsigned long long* __restrict__ cand,
                                                    const Ctl* __restrict__ ctl,
                                                    const float* __restrict__ roi,
                                                    float4* __restrict__ sbox) {
  __shared__ unsigned long long s[8192];
  int tid = threadIdx.x;
  unsigned cnt = ctl->candCount; if (cnt > CANDCAP) cnt = CANDCAP;
  #pragma unroll
  for (int r = 0; r < 8; ++r) {
    int i = r * 1024 + tid;
    s[i] = (i < (int)cnt) ? cand[i] : ~0ull;
  }
  __syncthreads();
  for (int k = 2; k <= 8192; k <<= 1)
    for (int j = k >> 1; j > 0; j >>= 1) {
      #pragma unroll
      for (int r = 0; r < 8; ++r) {
        int i = r * 1024 + tid; int l = i ^ j;
        if (l > i) {
          unsigned long long a = s[i], b = s[l];
          bool up = ((i & k) == 0);
          if ((a > b) == up) { s[i] = b; s[l] = a; }
        }
      }
      __syncthreads();
    }
  #pragma unroll
  for (int r = 0; r < 6; ++r) {
    int i = r * 1024 + tid;
    if (i < NPRE) {
      unsigned idx = (unsigned)(s[i] & 0xFFFFFFFFull);
      float4 b = make_float4(0.f, 0.f, 0.f, 0.f);
      if (idx < (unsigned)NANCH) b = *(const float4*)&roi[(size_t)idx * 4];
      sbox[i] = b;
    }
  }
}

// ---------------- K10a: parallel IoU mask matrix ----------------
__device__ __forceinline__ bool iou_gt(float4 A, float4 B) {
  float areaA = (A.z - A.x) * (A.w - A.y);
  float areaB = (B.z - B.x) * (B.w - B.y);
  float ih = fmaxf(fminf(A.z, B.z) - fmaxf(A.x, B.x), 0.f);
  float iw = fmaxf(fminf(A.w, B.w) - fmaxf(A.y, B.y), 0.f);
  float inter = ih * iw;
  return inter / (areaA + areaB - inter + 1e-9f) > 0.7f;
}

__global__ __launch_bounds__(256) void mask_kernel(const float4* __restrict__ sbox,
                                                   unsigned long long* __restrict__ M) {
  __shared__ float4 rb[64];
  __shared__ float4 cbx[256];
  const int c = blockIdx.x;
  const int tid = threadIdx.x;
  if (tid < 64) {
    int i = c * 64 + tid;
    rb[tid] = (i < NPRE) ? sbox[i] : make_float4(0.f, 0.f, 0.f, 0.f);
  }
  __syncthreads();
  const int rl = tid >> 2, q = tid & 3;
  const int i = c * 64 + rl;
  const float4 bi = rb[rl];
  for (int t = c >> 2; t < 24; ++t) {
    int j = t * 256 + tid;
    cbx[tid] = (j < NPRE) ? sbox[j] : make_float4(0.f, 0.f, 0.f, 0.f);
    __syncthreads();
    int w = t * 4 + q;
    if (w >= c && i < NPRE) {
      unsigned long long bits = 0ull;
      #pragma unroll 8
      for (int jj = 0; jj < 64; ++jj) {
        int jg = w * 64 + jj;
        float4 bj = cbx[q * 64 + jj];
        if (jg > i && jg < NPRE && iou_gt(bi, bj)) bits |= (1ull << jj);
      }
      M[(size_t)i * MROW + w] = bits;
    }
    __syncthreads();
  }
}

// ---------------- K10b: serial greedy resolve, v2 ----------------
__global__ __launch_bounds__(64) void resolve_kernel(const unsigned long long* __restrict__ M,
                                                     const Ctl* __restrict__ ctl,
                                                     const float4* __restrict__ sbox,
                                                     float* __restrict__ rois_out) {
  __shared__ unsigned long long remLDS[94];
  __shared__ int keepList[NPOST];
  __shared__ int keepCount;
  const int l = threadIdx.x;
  unsigned cnt = ctl->candCount; if (cnt > (unsigned)NPRE) cnt = NPRE;
  const int nvalid = (int)cnt;

  auto initw = [&](int w) -> unsigned long long {
    int lo = w * 64;
    if (lo + 64 <= nvalid) return 0ull;
    if (lo >= nvalid) return ~0ull;
    return (~0ull) << (nvalid - lo);
  };
  unsigned long long rem0 = initw(l);
  unsigned long long rem1 = (l < 30) ? initw(64 + l) : ~0ull;

  int keepTotal = 0;
  int cstop = 94;
  unsigned long long dw = M[(size_t)l * MROW + 0];

  for (int c = 0; c < 94; ++c) {
    unsigned long long dwN = 0ull;
    if (c + 1 < 94) dwN = M[(size_t)((c + 1) * 64 + l) * MROW + (c + 1)];

    unsigned long long remRep = (c < 64) ? __shfl(rem0, c) : __shfl(rem1, c - 64);

    #pragma unroll
    for (int kk = 0; kk < 64; kk += 16) {
      unsigned long long wv[16];
      #pragma unroll
      for (int t = 0; t < 16; ++t) wv[t] = __shfl(dw, kk + t);
      #pragma unroll
      for (int t = 0; t < 16; ++t) {
        if (!((remRep >> (kk + t)) & 1ull)) remRep |= wv[t];
      }
    }

    if (l == 0) remLDS[c] = remRep;
    if (c < 64) { if (l == c) rem0 = remRep; }
    else        { if (l == c - 64) rem1 = remRep; }
    keepTotal += (int)__popcll(~remRep);

    unsigned long long km = ~remRep;
    const size_t base = (size_t)c * 64;
    while (km) {
      int k0 = __ffsll((long long)km) - 1; km &= km - 1;
      int k1 = k0, k2 = k0, k3 = k0;
      if (km) { k1 = __ffsll((long long)km) - 1; km &= km - 1; }
      if (km) { k2 = __ffsll((long long)km) - 1; km &= km - 1; }
      if (km) { k3 = __ffsll((long long)km) - 1; km &= km - 1; }
      const unsigned long long* p0 = M + (base + k0) * MROW;
      const unsigned long long* p1 = M + (base + k1) * MROW;
      const unsigned long long* p2 = M + (base + k2) * MROW;
      const unsigned long long* p3 = M + (base + k3) * MROW;
      unsigned long long a0 = p0[l], a1 = p1[l], a2 = p2[l], a3 = p3[l];
      rem0 |= a0 | a1 | a2 | a3;
      if (l < 30) {
        unsigned long long b0 = p0[64 + l], b1 = p1[64 + l], b2 = p2[64 + l], b3 = p3[64 + l];
        rem1 |= b0 | b1 | b2 | b3;
      }
    }

    dw = dwN;
    if (keepTotal >= NPOST) { cstop = c + 1; break; }
  }

  __syncthreads();
  if (l == 0) {
    int ck = 0;
    for (int w = 0; w < cstop && ck < NPOST; ++w) {
      unsigned long long kw = ~remLDS[w];
      while (kw && ck < NPOST) {
        int r = __ffsll((long long)kw) - 1; kw &= kw - 1;
        keepList[ck++] = w * 64 + r;
      }
    }
    keepCount = ck;
  }
  __syncthreads();
  for (int s = l; s < NPOST; s += 64) {
    float4 b = make_float4(0.f, 0.f, 0.f, 0.f);
    if (s < keepCount) b = sbox[keepList[s]];
    *(float4*)&rois_out[(size_t)s * 4] = b;
  }
}

// ---------------- host ----------------
extern "C" void kernel_launch(void* const* d_in, const int* in_sizes, int n_in,
                              void* d_out, int out_size, void* d_ws, size_t ws_size,
                              hipStream_t stream) {
  const float* x  = (const float*)d_in[0];
  const float* w1 = (const float*)d_in[1];
  const float* b1 = (const float*)d_in[2];
  const float* sw = (const float*)d_in[3];
  const float* sb = (const float*)d_in[4];
  const float* lw = (const float*)d_in[5];
  const float* lb = (const float*)d_in[6];
  const int* ihp  = (const int*)d_in[7];
  const int* iwp  = (const int*)d_in[8];
  float* out = (float*)d_out;

  char* ws = (char*)d_ws;
  _Float16* wtapH = (_Float16*)(ws + WTH_OFF);
  _Float16* wtapL = (_Float16*)(ws + WTL_OFF);
  float* wx   = (float*)(ws + WX_OFF);
  _Float16* xh_alloc = (_Float16*)(ws + XH_OFF);
  _Float16* xl_alloc = (_Float16*)(ws + XL_OFF);
  _Float16* xh = xh_alloc + (size_t)XGUARD * 512;
  _Float16* xl = xl_alloc + (size_t)XGUARD * 512;
  float* h    = (float*)(ws + H_OFF);
  float* roi  = (float*)(ws + ROI_OFF);
  float* sc   = (float*)(ws + SC_OFF);
  Ctl*   ctl  = (Ctl*)(ws + CTL_OFF);
  unsigned long long* cand = (unsigned long long*)(ws + CAND_OFF);
  float4* sbox = (float4*)(ws + SBOX_OFF);
  unsigned long long* Mmask = (unsigned long long*)(ws + H_OFF);

  AnchorArg ab;
  {
    const double ratios[3] = {0.5, 1.0, 2.0};
    const double scales[3] = {8.0, 16.0, 32.0};
    for (int i = 0; i < 3; ++i)
      for (int j = 0; j < 3; ++j) {
        double hh = 16.0 * scales[j] * sqrt(ratios[i]);
        double wwd = 16.0 * scales[j] * sqrt(1.0 / ratios[i]);
        int a = i * 3 + j;
        ab.v[a * 4 + 0] = (float)(8.0 - hh / 2.0);
        ab.v[a * 4 + 1] = (float)(8.0 - wwd / 2.0);
        ab.v[a * 4 + 2] = (float)(8.0 + hh / 2.0);
        ab.v[a * 4 + 3] = (float)(8.0 + wwd / 2.0);
      }
  }

  float* rpn_loc   = out;                 // 136800*4
  float* rpn_score = out + 547200;        // 136800*2
  float* rois      = out + 820800;        // 300*4

  wx_kernel<<<108, 256, 0, stream>>>(sw, lw, wx, ctl);
  prep_w_kernel<<<512, 256, 0, stream>>>(w1, wtapH, wtapL);
  prep_x_kernel<<<XROWS_TOTAL / 64, 256, 0, stream>>>(x, xh_alloc, xl_alloc);
  conv1_mfma_kernel<<<dim3(4, PPS / 128), 256, 0, stream>>>(xh, xl, wtapH, wtapL, b1, h);
  heads_kernel<<<238, 256, 0, stream>>>(h, wx, sb, lb, rpn_loc, rpn_score, roi, sc, ab, ihp, iwp);
  for (int p = 0; p < 3; ++p)
    hist_scan_kernel<<<HGRID, 256, 0, stream>>>(sc, ctl, p);
  compact_kernel<<<535, 256, 0, stream>>>(sc, ctl, cand);
  sort_kernel<<<1, 1024, 0, stream>>>(cand, ctl, roi, sbox);
  mask_kernel<<<94, 256, 0, stream>>>(sbox, Mmask);
  resolve_kernel<<<1, 64, 0, stream>>>(Mmask, ctl, sbox, rois);
}

// Round 6
// 880.185 us; speedup vs baseline: 1.0308x; 1.0308x over previous
//
#include <hip/hip_runtime.h>
#include <math.h>
#include <stdint.h>

// ---------------- problem constants ----------------
#define CHH 100
#define CWW 152
#define NPIX 15200          // 100*152
#define NANCH 136800        // NPIX*9
#define NPRE 6000
#define NPOST 300
#define CANDCAP 8192
#define MROW 96             // u64 words per mask row (94 used, padded)

// padded pixel geometry for the MFMA conv: pp = (py+1)*154 + (px+1)
#define PSTRIDE 154
#define PPVALID 16016       // 154*104 region containing all shifted accesses
#define PPS 16128           // padded to 126 tiles of 128
#define XGUARD 256          // zero guard rows each side of the [0,PPS) range
#define XROWS_TOTAL (PPS + 2*XGUARD)   // 16640

// LDS tile inner dim: 32 (the b128 fragment reads are footprint-BW-bound; padding can't help
// and only breaks the contiguous staging writes — measured R4: LPAD=40 doubled conflicts)
#define LPAD 32

// ---------------- ws layout (bytes) ----------------
#define WTH_OFF  0ull                  // w taps hi: [9][512][512] f16 = 4,718,592
#define WTL_OFF  4718592ull            // w taps lo
#define WX_OFF   9437184ull            // 1x1 weights transposed: [512][54] f32
#define XH_OFF   9547776ull            // x hi plane: [16640][512] f16 = 17,039,360
#define XL_OFF   26587136ull           // x lo plane
#define H_OFF    43626496ull           // hidden: [512][16128] f32 = 33,030,144 (reused as NMS mask)
#define ROI_OFF  76656640ull           // roi: [136800][4] f32
#define SC_OFF   78845440ull           // sc: [136800] f32
#define CTL_OFF  79392640ull           // Ctl struct
#define CAND_OFF 79396736ull           // cand: [8192] u64
#define SBOX_OFF 79462272ull           // sorted boxes: [6000] float4

typedef _Float16 f16x8 __attribute__((ext_vector_type(8)));
typedef float    f32x4 __attribute__((ext_vector_type(4)));

struct Ctl {
  unsigned hist[256];
  unsigned prefix;
  unsigned countGreater;
  unsigned candCount;
  unsigned done;
};

struct AnchorArg { float v[36]; };

__device__ __forceinline__ unsigned mono_key(float f) {
  unsigned u = __float_as_uint(f);
  return u ^ ((u & 0x80000000u) ? 0xFFFFFFFFu : 0x80000000u);
}

// ---------------- K1: split conv1 weights into per-tap f16 hi/lo planes (+wx, +ctl init) --
__global__ __launch_bounds__(256) void prep_w_kernel(const float* __restrict__ w1,
                                                     _Float16* __restrict__ wtapH,
                                                     _Float16* __restrict__ wtapL,
                                                     const float* __restrict__ score_w,
                                                     const float* __restrict__ loc_w,
                                                     float* __restrict__ wx,
                                                     Ctl* __restrict__ ctl) {
  __shared__ float wl[4608];
  const int oc = blockIdx.x, tid = threadIdx.x;
  if (oc == 0) {
    ctl->hist[tid] = 0u;
    if (tid == 0) { ctl->prefix = 0u; ctl->countGreater = 0u; ctl->candCount = 0u; ctl->done = 0u; }
  }
  // combined 1x1 weights for this ic (=oc): wx[ic][0..53]
  if (tid < 54) wx[oc * 54 + tid] = (tid < 18) ? score_w[tid * 512 + oc] : loc_w[(tid - 18) * 512 + oc];
  for (int li = tid; li < 4608; li += 256) wl[li] = w1[(size_t)oc * 4608 + li];
  __syncthreads();
  for (int t = 0; t < 9; ++t) {
    size_t ob = ((size_t)t * 512 + oc) * 512;
    for (int ic = tid; ic < 512; ic += 256) {
      float v = wl[ic * 9 + t];
      _Float16 hi = (_Float16)v;
      wtapH[ob + ic] = hi;
      wtapL[ob + ic] = (_Float16)(v - (float)hi);
    }
  }
}

// ---------------- K2: transpose+pad+split input: x [512][15200] -> xh/xl [16640][512] ----
__global__ __launch_bounds__(256) void prep_x_kernel(const float* __restrict__ x,
                                                     _Float16* __restrict__ xh,
                                                     _Float16* __restrict__ xl) {
  __shared__ float tile[64][65];
  const int tid = threadIdx.x;
  const int r0 = blockIdx.x * 64;                // alloc-row base (0..16640)
  for (int ic0 = 0; ic0 < 512; ic0 += 64) {
    #pragma unroll
    for (int it = 0; it < 16; ++it) {
      int li = it * 256 + tid;
      int i = li >> 6, j = li & 63;
      int pp = r0 + j - XGUARD;
      float v = 0.f;
      if (pp >= 0 && pp < PPVALID) {
        int rowp = pp / PSTRIDE, colp = pp - rowp * PSTRIDE;
        if (rowp >= 1 && rowp <= 100 && colp >= 1 && colp <= 152) {
          int p = (rowp - 1) * CWW + (colp - 1);
          v = x[(size_t)(ic0 + i) * NPIX + p];
        }
      }
      tile[i][j] = v;
    }
    __syncthreads();
    int j = tid >> 2, cq = tid & 3;
    size_t ob = (size_t)(r0 + j) * 512 + ic0 + cq * 16;
    f16x8 vh0, vh1, vl0, vl1;
    #pragma unroll
    for (int c = 0; c < 8; ++c) {
      float v = tile[cq * 16 + c][j];
      _Float16 hi = (_Float16)v;
      vh0[c] = hi; vl0[c] = (_Float16)(v - (float)hi);
    }
    #pragma unroll
    for (int c = 0; c < 8; ++c) {
      float v = tile[cq * 16 + 8 + c][j];
      _Float16 hi = (_Float16)v;
      vh1[c] = hi; vl1[c] = (_Float16)(v - (float)hi);
    }
    *(f16x8*)&xh[ob]     = vh0;
    *(f16x8*)&xh[ob + 8] = vh1;
    *(f16x8*)&xl[ob]     = vl0;
    *(f16x8*)&xl[ob + 8] = vl1;
    __syncthreads();
  }
}

// ---------------- K3: conv1 as split-f16 MFMA implicit GEMM ----------------
// Linear grid with XCD-swizzle: XCD x (bid%8) always gets oc-tile (bid&3) ->
// each XCD's 2.36 MB weight slice stays L2-resident instead of 9.4 MB thrash.
__global__ __launch_bounds__(256) void conv1_mfma_kernel(const _Float16* __restrict__ xh,
                                                         const _Float16* __restrict__ xl,
                                                         const _Float16* __restrict__ wtapH,
                                                         const _Float16* __restrict__ wtapL,
                                                         const float* __restrict__ bias,
                                                         float* __restrict__ h) {
  __shared__ _Float16 Ah[128][LPAD], Al[128][LPAD], Bh[128][LPAD], Bl[128][LPAD];
  __shared__ float bsm[128];
  const int tid = threadIdx.x;
  const int bid = blockIdx.x;
  const int oc0 = (bid & 3) * 128;
  const int pp0 = (((bid >> 3) << 1) + ((bid >> 2) & 1)) * 128;
  if (tid < 128) bsm[tid] = bias[oc0 + tid];

  const int lane = tid & 63;
  const int n16 = lane & 15, quad = lane >> 4;
  const int wid = tid >> 6;
  const int wm = wid >> 1, wn = wid & 1;
  const int srow = tid >> 2, sq = tid & 3;

  f32x4 acc[4][4];
  #pragma unroll
  for (int mi = 0; mi < 4; ++mi)
    #pragma unroll
    for (int ni = 0; ni < 4; ++ni) acc[mi][ni] = (f32x4){0.f, 0.f, 0.f, 0.f};

  for (int t = 0; t < 9; ++t) {
    const int dsh = (t / 3 - 1) * PSTRIDE + (t % 3) - 1;
    const size_t wbase = ((size_t)t * 512 + oc0) * 512;
    for (int icb = 0; icb < 512; icb += 32) {
      #pragma unroll
      for (int hf = 0; hf < 2; ++hf) {
        int row = hf * 64 + srow;
        size_t wo = wbase + (size_t)row * 512 + icb + sq * 8;
        *(f16x8*)&Ah[row][sq * 8] = *(const f16x8*)&wtapH[wo];
        *(f16x8*)&Al[row][sq * 8] = *(const f16x8*)&wtapL[wo];
        size_t xo = (size_t)(pp0 + row + dsh) * 512 + icb + sq * 8;
        *(f16x8*)&Bh[row][sq * 8] = *(const f16x8*)&xh[xo];
        *(f16x8*)&Bl[row][sq * 8] = *(const f16x8*)&xl[xo];
      }
      __syncthreads();
      f16x8 ah[4], al[4], bh[4], bl[4];
      #pragma unroll
      for (int mi = 0; mi < 4; ++mi) {
        ah[mi] = *(const f16x8*)&Ah[wm * 64 + mi * 16 + n16][quad * 8];
        al[mi] = *(const f16x8*)&Al[wm * 64 + mi * 16 + n16][quad * 8];
      }
      #pragma unroll
      for (int ni = 0; ni < 4; ++ni) {
        bh[ni] = *(const f16x8*)&Bh[wn * 64 + ni * 16 + n16][quad * 8];
        bl[ni] = *(const f16x8*)&Bl[wn * 64 + ni * 16 + n16][quad * 8];
      }
      #pragma unroll
      for (int mi = 0; mi < 4; ++mi)
        #pragma unroll
        for (int ni = 0; ni < 4; ++ni) {
          acc[mi][ni] = __builtin_amdgcn_mfma_f32_16x16x32_f16(ah[mi], bh[ni], acc[mi][ni], 0, 0, 0);
          acc[mi][ni] = __builtin_amdgcn_mfma_f32_16x16x32_f16(ah[mi], bl[ni], acc[mi][ni], 0, 0, 0);
          acc[mi][ni] = __builtin_amdgcn_mfma_f32_16x16x32_f16(al[mi], bh[ni], acc[mi][ni], 0, 0, 0);
        }
      __syncthreads();
    }
  }
  #pragma unroll
  for (int mi = 0; mi < 4; ++mi) {
    int ocb = wm * 64 + mi * 16 + quad * 4;
    #pragma unroll
    for (int ni = 0; ni < 4; ++ni) {
      int pp = pp0 + wn * 64 + ni * 16 + n16;
      #pragma unroll
      for (int r = 0; r < 4; ++r) {
        float v = acc[mi][ni][r] + bsm[ocb + r];
        h[(size_t)(oc0 + ocb + r) * PPS + pp] = fmaxf(v, 0.f);
      }
    }
  }
}

// ---------------- K4: 1x1 heads + softmax + loc2bbox + clip + valid ----------------
__global__ __launch_bounds__(256) void heads_kernel(const float* __restrict__ h,
                                                    const float* __restrict__ wx,
                                                    const float* __restrict__ score_b,
                                                    const float* __restrict__ loc_b,
                                                    float* __restrict__ rpn_loc,
                                                    float* __restrict__ rpn_score,
                                                    float* __restrict__ roi,
                                                    float* __restrict__ sc,
                                                    AnchorArg ab,
                                                    const int* __restrict__ ihp,
                                                    const int* __restrict__ iwp) {
  __shared__ float hs[64][64];
  __shared__ float red[54][64];
  const int tid = threadIdx.x;
  const int p0 = blockIdx.x * 64;
  const int pxl = tid & 63, icq = tid >> 6;
  int pcol = p0 + pxl;
  bool pok = pcol < NPIX;
  int ppl = 0;
  if (pok) ppl = (pcol / CWW + 1) * PSTRIDE + (pcol % CWW) + 1;

  float acc[54];
  #pragma unroll
  for (int o = 0; o < 54; ++o) acc[o] = 0.f;

  for (int c = 0; c < 8; ++c) {
    int ic0 = c * 64;
    #pragma unroll
    for (int r = 0; r < 16; ++r) {
      int i = r * 4 + icq;
      hs[i][pxl] = pok ? h[(size_t)(ic0 + i) * PPS + ppl] : 0.f;
    }
    __syncthreads();
    #pragma unroll
    for (int k = 0; k < 16; ++k) {
      int icl = icq + k * 4;
      float v = hs[icl][pxl];
      const float* wrow = &wx[(ic0 + icl) * 54];
      #pragma unroll
      for (int o = 0; o < 54; ++o) acc[o] += wrow[o] * v;
    }
    __syncthreads();
  }
  for (int w = 0; w < 4; ++w) {
    if (icq == w) {
      if (w == 0) {
        #pragma unroll
        for (int o = 0; o < 54; ++o) red[o][pxl] = acc[o];
      } else {
        #pragma unroll
        for (int o = 0; o < 54; ++o) red[o][pxl] += acc[o];
      }
    }
    __syncthreads();
  }

  const float fH = (float)(*ihp);
  const float fW = (float)(*iwp);
  for (int it = tid; it < 576; it += 256) {
    #pragma clang fp contract(off)
    int pl = it / 9, a = it - pl * 9;
    int p = p0 + pl;
    if (p >= NPIX) continue;
    float s0 = red[a * 2][pl]     + score_b[a * 2];
    float s1 = red[a * 2 + 1][pl] + score_b[a * 2 + 1];
    float dy = red[18 + a * 4][pl]     + loc_b[a * 4];
    float dx = red[18 + a * 4 + 1][pl] + loc_b[a * 4 + 1];
    float dh = red[18 + a * 4 + 2][pl] + loc_b[a * 4 + 2];
    float dw = red[18 + a * 4 + 3][pl] + loc_b[a * 4 + 3];
    int row = p * 9 + a;
    *(float2*)&rpn_score[row * 2] = make_float2(s0, s1);
    *(float4*)&rpn_loc[(size_t)row * 4] = make_float4(dy, dx, dh, dw);
    int ypix = p / CWW, xpix = p - ypix * CWW;
    float sy = (float)(ypix * 16), sx = (float)(xpix * 16);
    float a0 = sy + ab.v[a * 4 + 0], a1 = sx + ab.v[a * 4 + 1];
    float a2 = sy + ab.v[a * 4 + 2], a3 = sx + ab.v[a * 4 + 3];
    float ha = a2 - a0, wa = a3 - a1;
    float cy = a0 + 0.5f * ha, cx = a1 + 0.5f * wa;
    float cy2 = dy * ha + cy, cx2 = dx * wa + cx;
    float h2 = expf(dh) * ha, w2 = expf(dw) * wa;
    float y1 = cy2 - 0.5f * h2, x1 = cx2 - 0.5f * w2;
    float y2 = cy2 + 0.5f * h2, x2 = cx2 + 0.5f * w2;
    y1 = fminf(fmaxf(y1, 0.f), fH); x1 = fminf(fmaxf(x1, 0.f), fW);
    y2 = fminf(fmaxf(y2, 0.f), fH); x2 = fminf(fmaxf(x2, 0.f), fW);
    *(float4*)&roi[(size_t)row * 4] = make_float4(y1, x1, y2, x2);
    bool valid = (y2 - y1 >= 16.f) && (x2 - x1 >= 16.f);
    float m  = fmaxf(s0, s1);
    float e0 = expf(s0 - m), e1 = expf(s1 - m);
    float fg = e1 / (e0 + e1);
    sc[row] = valid ? fg : -__builtin_inff();
  }
}

// ---------------- K5: fused radix histogram + last-block scan ----------------
#define HGRID 120
__global__ __launch_bounds__(256) void hist_scan_kernel(const float* __restrict__ sc,
                                                        Ctl* __restrict__ ctl, int pass) {
  __shared__ unsigned hloc[256];
  __shared__ unsigned ticket_s;
  int tid = threadIdx.x;
  hloc[tid] = 0u;
  __syncthreads();
  unsigned prefix = ctl->prefix;
  for (int i = blockIdx.x * 256 + tid; i < NANCH; i += HGRID * 256) {
    unsigned m = mono_key(sc[i]);
    bool pred = (pass == 0) || ((m >> (32 - 8 * pass)) == prefix);
    if (pred) atomicAdd(&hloc[(m >> (24 - 8 * pass)) & 255u], 1u);
  }
  __syncthreads();
  if (hloc[tid]) atomicAdd(&ctl->hist[tid], hloc[tid]);
  __threadfence();
  __syncthreads();
  if (tid == 0) ticket_s = atomicAdd(&ctl->done, 1u);
  __syncthreads();
  if (ticket_s != HGRID - 1) return;
  unsigned v = atomicExch(&ctl->hist[tid], 0u);
  hloc[tid] = v;
  __syncthreads();
  for (int d = 1; d < 256; d <<= 1) {
    unsigned t2 = hloc[tid] + ((tid + d < 256) ? hloc[tid + d] : 0u);
    __syncthreads();
    hloc[tid] = t2;
    __syncthreads();
  }
  unsigned G = ctl->countGreater;
  unsigned inclT = hloc[tid];
  unsigned inclN = (tid < 255) ? hloc[tid + 1] : 0u;
  if (G + inclT >= (unsigned)NPRE && G + inclN < (unsigned)NPRE) {
    ctl->prefix = (prefix << 8) | (unsigned)tid;
    ctl->countGreater = G + inclN;
  }
  if (tid == 0) atomicExch(&ctl->done, 0u);
}

// ---------------- K6: compact candidates ----------------
__global__ __launch_bounds__(256) void compact_kernel(const float* __restrict__ sc,
                                                      Ctl* __restrict__ ctl,
                                                      unsigned long long* __restrict__ cand) {
  int i = blockIdx.x * 256 + threadIdx.x;
  unsigned prefix = ctl->prefix;
  bool pred = false; unsigned m = 0;
  if (i < NANCH) { m = mono_key(sc[i]); pred = ((m >> 8) >= prefix); }
  unsigned long long mask = __ballot(pred);
  if (mask) {
    int lane = threadIdx.x & 63;
    int leader = __ffsll((long long)mask) - 1;
    unsigned base = 0;
    if (lane == leader) base = atomicAdd(&ctl->candCount, (unsigned)__popcll(mask));
    base = __shfl(base, leader);
    if (pred) {
      unsigned slot = base + (unsigned)__popcll(mask & ((1ull << lane) - 1ull));
      if (slot < CANDCAP)
        cand[slot] = (((unsigned long long)(~m)) << 32) | (unsigned)i;
    }
  }
}

// ---------------- K7: parallel rank-scatter (replaces single-block bitonic sort) ----------
// rank(i) = #{j: key_j < key_i} over unique u64 keys == position in ascending sort.
__global__ __launch_bounds__(256) void rank_kernel(const unsigned long long* __restrict__ cand,
                                                   const Ctl* __restrict__ ctl,
                                                   const float* __restrict__ roi,
                                                   float4* __restrict__ sbox) {
  __shared__ unsigned long long kb[2048];
  __shared__ unsigned pc[64][5];
  const int tid = threadIdx.x;
  const int c = tid & 63, q = tid >> 6;
  const int slot = blockIdx.x * 64 + c;
  unsigned nv = ctl->candCount; if (nv > CANDCAP) nv = CANDCAP;
  unsigned long long K = (slot < (int)nv) ? cand[slot] : ~0ull;
  unsigned cnt = 0;
  for (unsigned c0 = 0; c0 < nv; c0 += 2048) {
    for (int i = tid; i < 2048; i += 256) {
      unsigned g = c0 + (unsigned)i;
      kb[i] = (g < nv) ? cand[g] : ~0ull;
    }
    __syncthreads();
    int lim = (int)(nv - c0); if (lim > 2048) lim = 2048;
    int i0 = q * 512, ie = i0 + 512; if (ie > lim) ie = lim;
    for (int i = i0; i < ie; ++i) cnt += (kb[i] < K) ? 1u : 0u;
    __syncthreads();
  }
  pc[c][q] = cnt;
  __syncthreads();
  if (q == 0) {
    unsigned rank = pc[c][0] + pc[c][1] + pc[c][2] + pc[c][3];
    if (slot < (int)nv && rank < NPRE) {
      unsigned idx = (unsigned)(K & 0xFFFFFFFFull);
      sbox[rank] = *(const float4*)&roi[(size_t)idx * 4];
    }
  } else if (q == 1) {
    int nvR = (nv < (unsigned)NPRE) ? (int)nv : NPRE;
    if (slot >= nvR && slot < NPRE) sbox[slot] = make_float4(0.f, 0.f, 0.f, 0.f);
  }
}

// ---------------- K8a: parallel IoU mask matrix ----------------
__device__ __forceinline__ bool iou_gt(float4 A, float4 B) {
  float areaA = (A.z - A.x) * (A.w - A.y);
  float areaB = (B.z - B.x) * (B.w - B.y);
  float ih = fmaxf(fminf(A.z, B.z) - fmaxf(A.x, B.x), 0.f);
  float iw = fmaxf(fminf(A.w, B.w) - fmaxf(A.y, B.y), 0.f);
  float inter = ih * iw;
  return inter / (areaA + areaB - inter + 1e-9f) > 0.7f;
}

__global__ __launch_bounds__(256) void mask_kernel(const float4* __restrict__ sbox,
                                                   unsigned long long* __restrict__ M) {
  __shared__ float4 rb[64];
  __shared__ float4 cbx[256];
  const int c = blockIdx.x;
  const int tid = threadIdx.x;
  if (tid < 64) {
    int i = c * 64 + tid;
    rb[tid] = (i < NPRE) ? sbox[i] : make_float4(0.f, 0.f, 0.f, 0.f);
  }
  __syncthreads();
  const int rl = tid >> 2, q = tid & 3;
  const int i = c * 64 + rl;
  const float4 bi = rb[rl];
  for (int t = c >> 2; t < 24; ++t) {
    int j = t * 256 + tid;
    cbx[tid] = (j < NPRE) ? sbox[j] : make_float4(0.f, 0.f, 0.f, 0.f);
    __syncthreads();
    int w = t * 4 + q;
    if (w >= c && i < NPRE) {
      unsigned long long bits = 0ull;
      #pragma unroll 8
      for (int jj = 0; jj < 64; ++jj) {
        int jg = w * 64 + jj;
        float4 bj = cbx[q * 64 + jj];
        if (jg > i && jg < NPRE && iou_gt(bi, bj)) bits |= (1ull << jj);
      }
      M[(size_t)i * MROW + w] = bits;
    }
    __syncthreads();
  }
}

// ---------------- K8b: serial greedy resolve ----------------
__global__ __launch_bounds__(64) void resolve_kernel(const unsigned long long* __restrict__ M,
                                                     const Ctl* __restrict__ ctl,
                                                     const float4* __restrict__ sbox,
                                                     float* __restrict__ rois_out) {
  __shared__ unsigned long long remLDS[94];
  __shared__ int keepList[NPOST];
  __shared__ int keepCount;
  const int l = threadIdx.x;
  unsigned cnt = ctl->candCount; if (cnt > (unsigned)NPRE) cnt = NPRE;
  const int nvalid = (int)cnt;

  auto initw = [&](int w) -> unsigned long long {
    int lo = w * 64;
    if (lo + 64 <= nvalid) return 0ull;
    if (lo >= nvalid) return ~0ull;
    return (~0ull) << (nvalid - lo);
  };
  unsigned long long rem0 = initw(l);
  unsigned long long rem1 = (l < 30) ? initw(64 + l) : ~0ull;

  int keepTotal = 0;
  int cstop = 94;
  unsigned long long dw = M[(size_t)l * MROW + 0];

  for (int c = 0; c < 94; ++c) {
    unsigned long long dwN = 0ull;
    if (c + 1 < 94) dwN = M[(size_t)((c + 1) * 64 + l) * MROW + (c + 1)];

    unsigned long long remRep = (c < 64) ? __shfl(rem0, c) : __shfl(rem1, c - 64);

    #pragma unroll
    for (int kk = 0; kk < 64; kk += 16) {
      unsigned long long wv[16];
      #pragma unroll
      for (int t = 0; t < 16; ++t) wv[t] = __shfl(dw, kk + t);
      #pragma unroll
      for (int t = 0; t < 16; ++t) {
        if (!((remRep >> (kk + t)) & 1ull)) remRep |= wv[t];
      }
    }

    if (l == 0) remLDS[c] = remRep;
    if (c < 64) { if (l == c) rem0 = remRep; }
    else        { if (l == c - 64) rem1 = remRep; }
    keepTotal += (int)__popcll(~remRep);

    unsigned long long km = ~remRep;
    const size_t base = (size_t)c * 64;
    while (km) {
      int k0 = __ffsll((long long)km) - 1; km &= km - 1;
      int k1 = k0, k2 = k0, k3 = k0;
      if (km) { k1 = __ffsll((long long)km) - 1; km &= km - 1; }
      if (km) { k2 = __ffsll((long long)km) - 1; km &= km - 1; }
      if (km) { k3 = __ffsll((long long)km) - 1; km &= km - 1; }
      const unsigned long long* p0 = M + (base + k0) * MROW;
      const unsigned long long* p1 = M + (base + k1) * MROW;
      const unsigned long long* p2 = M + (base + k2) * MROW;
      const unsigned long long* p3 = M + (base + k3) * MROW;
      unsigned long long a0 = p0[l], a1 = p1[l], a2 = p2[l], a3 = p3[l];
      rem0 |= a0 | a1 | a2 | a3;
      if (l < 30) {
        unsigned long long b0 = p0[64 + l], b1 = p1[64 + l], b2 = p2[64 + l], b3 = p3[64 + l];
        rem1 |= b0 | b1 | b2 | b3;
      }
    }

    dw = dwN;
    if (keepTotal >= NPOST) { cstop = c + 1; break; }
  }

  __syncthreads();
  if (l == 0) {
    int ck = 0;
    for (int w = 0; w < cstop && ck < NPOST; ++w) {
      unsigned long long kw = ~remLDS[w];
      while (kw && ck < NPOST) {
        int r = __ffsll((long long)kw) - 1; kw &= kw - 1;
        keepList[ck++] = w * 64 + r;
      }
    }
    keepCount = ck;
  }
  __syncthreads();
  for (int s = l; s < NPOST; s += 64) {
    float4 b = make_float4(0.f, 0.f, 0.f, 0.f);
    if (s < keepCount) b = sbox[keepList[s]];
    *(float4*)&rois_out[(size_t)s * 4] = b;
  }
}

// ---------------- host ----------------
extern "C" void kernel_launch(void* const* d_in, const int* in_sizes, int n_in,
                              void* d_out, int out_size, void* d_ws, size_t ws_size,
                              hipStream_t stream) {
  const float* x  = (const float*)d_in[0];
  const float* w1 = (const float*)d_in[1];
  const float* b1 = (const float*)d_in[2];
  const float* sw = (const float*)d_in[3];
  const float* sb = (const float*)d_in[4];
  const float* lw = (const float*)d_in[5];
  const float* lb = (const float*)d_in[6];
  const int* ihp  = (const int*)d_in[7];
  const int* iwp  = (const int*)d_in[8];
  float* out = (float*)d_out;

  char* ws = (char*)d_ws;
  _Float16* wtapH = (_Float16*)(ws + WTH_OFF);
  _Float16* wtapL = (_Float16*)(ws + WTL_OFF);
  float* wx   = (float*)(ws + WX_OFF);
  _Float16* xh_alloc = (_Float16*)(ws + XH_OFF);
  _Float16* xl_alloc = (_Float16*)(ws + XL_OFF);
  _Float16* xh = xh_alloc + (size_t)XGUARD * 512;
  _Float16* xl = xl_alloc + (size_t)XGUARD * 512;
  float* h    = (float*)(ws + H_OFF);
  float* roi  = (float*)(ws + ROI_OFF);
  float* sc   = (float*)(ws + SC_OFF);
  Ctl*   ctl  = (Ctl*)(ws + CTL_OFF);
  unsigned long long* cand = (unsigned long long*)(ws + CAND_OFF);
  float4* sbox = (float4*)(ws + SBOX_OFF);
  unsigned long long* Mmask = (unsigned long long*)(ws + H_OFF);

  AnchorArg ab;
  {
    const double ratios[3] = {0.5, 1.0, 2.0};
    const double scales[3] = {8.0, 16.0, 32.0};
    for (int i = 0; i < 3; ++i)
      for (int j = 0; j < 3; ++j) {
        double hh = 16.0 * scales[j] * sqrt(ratios[i]);
        double wwd = 16.0 * scales[j] * sqrt(1.0 / ratios[i]);
        int a = i * 3 + j;
        ab.v[a * 4 + 0] = (float)(8.0 - hh / 2.0);
        ab.v[a * 4 + 1] = (float)(8.0 - wwd / 2.0);
        ab.v[a * 4 + 2] = (float)(8.0 + hh / 2.0);
        ab.v[a * 4 + 3] = (float)(8.0 + wwd / 2.0);
      }
  }

  float* rpn_loc   = out;                 // 136800*4
  float* rpn_score = out + 547200;        // 136800*2
  float* rois      = out + 820800;        // 300*4

  prep_w_kernel<<<512, 256, 0, stream>>>(w1, wtapH, wtapL, sw, lw, wx, ctl);
  prep_x_kernel<<<XROWS_TOTAL / 64, 256, 0, stream>>>(x, xh_alloc, xl_alloc);
  conv1_mfma_kernel<<<504, 256, 0, stream>>>(xh, xl, wtapH, wtapL, b1, h);
  heads_kernel<<<238, 256, 0, stream>>>(h, wx, sb, lb, rpn_loc, rpn_score, roi, sc, ab, ihp, iwp);
  for (int p = 0; p < 3; ++p)
    hist_scan_kernel<<<HGRID, 256, 0, stream>>>(sc, ctl, p);
  compact_kernel<<<535, 256, 0, stream>>>(sc, ctl, cand);
  rank_kernel<<<CANDCAP / 64, 256, 0, stream>>>(cand, ctl, roi, sbox);
  mask_kernel<<<94, 256, 0, stream>>>(sbox, Mmask);
  resolve_kernel<<<1, 64, 0, stream>>>(Mmask, ctl, sbox, rois);
}